// Round 9
// baseline (1150.022 us; speedup 1.0000x reference)
//
#include <hip/hip_runtime.h>
#include <hip/hip_bf16.h>

#define DM 1024
#define QLEN 512
#define VLEN 80
#define BQTOT 32768   // B*Q
#define BVTOT 5120    // B*V

typedef __attribute__((ext_vector_type(8))) short s16x8;
typedef __attribute__((ext_vector_type(4))) short s16x4;
typedef __attribute__((ext_vector_type(4))) float f32x4;
typedef __attribute__((ext_vector_type(8))) __bf16 bf16x8;

__device__ inline short f2bf(float f) {
    __bf16 h = (__bf16)f;
    return __builtin_bit_cast(short, h);
}
__device__ inline float bf2f(short s) {
    unsigned u = ((unsigned)(unsigned short)s) << 16;
    return __builtin_bit_cast(float, u);
}

// ---------------- fp32 -> bf16 bulk convert (8 elems/thread) ----------------
__global__ __launch_bounds__(256)
void conv_k(const float* __restrict__ in, short* __restrict__ out, int n8)
{
    const int i = blockIdx.x * 256 + threadIdx.x;
    if (i >= n8) return;
    const float4 a = ((const float4*)in)[(size_t)i * 2];
    const float4 b = ((const float4*)in)[(size_t)i * 2 + 1];
    s16x8 p;
    p[0] = f2bf(a.x); p[1] = f2bf(a.y); p[2] = f2bf(a.z); p[3] = f2bf(a.w);
    p[4] = f2bf(b.x); p[5] = f2bf(b.y); p[6] = f2bf(b.z); p[7] = f2bf(b.w);
    ((s16x8*)out)[i] = p;
}

// ---------------- concat two fp32 vectors ----------------
__global__ __launch_bounds__(256)
void cat_k(const float* __restrict__ a, const float* __restrict__ b,
           float* __restrict__ o, int n)
{
    const int i = blockIdx.x * 256 + threadIdx.x;
    o[i] = (i < n) ? a[i] : b[i - n];
}

// ---------------- weight transpose + bf16 convert: W[K][N] -> WT[N][K] ----------------
__global__ __launch_bounds__(256)
void transp_k(const float* __restrict__ W, short* __restrict__ WT, int K, int N)
{
    __shared__ float s[32][33];
    const int n0 = blockIdx.x * 32, k0 = blockIdx.y * 32;
    const int tx = threadIdx.x & 31, ty = threadIdx.x >> 5;
#pragma unroll
    for (int j = 0; j < 4; j++)
        s[ty + j * 8][tx] = W[(size_t)(k0 + ty + j * 8) * N + n0 + tx];
    __syncthreads();
#pragma unroll
    for (int j = 0; j < 4; j++) {
        int r = ty + j * 8;
        WT[(size_t)(n0 + r) * K + k0 + tx] = f2bf(s[tx][r]);
    }
}

// ---------------- 256x256 8-phase bf16 MFMA GEMM ----------------
// R5 XCD swizzle (m-major chunks: A-panel L2-local per XCD) + pointer-increment
// staging + max-lead stage rotation; vmcnt(4) guards at ph4/ph8 only.
// EPI==1 (H-stream) writes NON-TEMPORAL so the 128MB write stream does not
// evict the B weight panel from L3 (R8 diagnosis: w1T re-fetched ~15x).
// EPI:  0 = bf16 out = acc+bias
//       1 = bf16 out = relu(acc+bias)   [nt store]
//       2 = f32 out = acc+bias+resid_f32
//       3 = f32 out = acc+bias+resid_bf16
//       4 = f32 out = acc+resid_f32 (no bias)
//       5 = bf16 out = acc+bias+resid_bf16

#define STG(p, pb, d) do { \
    __builtin_amdgcn_global_load_lds((const __attribute__((address_space(1))) void*)(p), \
        (__attribute__((address_space(3))) void*)(d), 16, 0, 0); \
    __builtin_amdgcn_global_load_lds((const __attribute__((address_space(1))) void*)(pb), \
        (__attribute__((address_space(3))) void*)((d) + 512), 16, 0, 0); \
} while (0)

#define READ_B(db) do { \
    _Pragma("unroll") for (int n = 0; n < 4; n++) { \
        const int lb = ((wc & 1) << 6) + la15 + n * 16; \
        _Pragma("unroll") for (int ks = 0; ks < 2; ks++) \
            bfr[n][ks] = *(const bf16x8*)&Bs[db][wc >> 1][lb * 64 + kx[ks]]; \
    } } while (0)

#define READ_AQ(db, q, dst) do { \
    _Pragma("unroll") for (int mm = 0; mm < 2; mm++) { \
        const int lr2 = la15 + ((q) * 2 + mm) * 16; \
        _Pragma("unroll") for (int ks = 0; ks < 2; ks++) \
            dst[mm][ks] = *(const bf16x8*)&As[db][wr][lr2 * 64 + kx[ks]]; \
    } } while (0)

#define MFMA16Q(q, src) do { \
    __builtin_amdgcn_s_setprio(1); \
    _Pragma("unroll") for (int mm = 0; mm < 2; mm++) \
    _Pragma("unroll") for (int n = 0; n < 4; n++) \
    _Pragma("unroll") for (int ks = 0; ks < 2; ks++) \
        acc[(q) * 2 + mm][n] = __builtin_amdgcn_mfma_f32_16x16x32_bf16( \
            src[mm][ks], bfr[n][ks], acc[(q) * 2 + mm][n], 0, 0, 0); \
    __builtin_amdgcn_s_setprio(0); \
} while (0)

#define OPEN_PHASE() do { \
    __builtin_amdgcn_s_barrier(); \
    asm volatile("s_waitcnt lgkmcnt(0)" ::: "memory"); \
    __builtin_amdgcn_sched_barrier(0); \
} while (0)

#define ADV_A() do { pA0 += 64; pA0b += 64; pA1 += 64; pA1b += 64; } while (0)
#define ADV_B() do { pB0 += 64; pB0b += 64; pB1 += 64; pB1b += 64; } while (0)

template<int EPI>
__global__ __launch_bounds__(512, 1)
void gemm7_k(const short* __restrict__ A, const short* __restrict__ BT,
             const float* __restrict__ bias, const void* __restrict__ resid,
             void* __restrict__ outp, int M, int N, int K, int lda, int ldb, int NT)
{
    __shared__ __align__(16) short As[2][2][8192];   // [kt parity][half][128*64]
    __shared__ __align__(16) short Bs[2][2][8192];

    const int tid = threadIdx.x;
    const int lane = tid & 63;
    const int wid = tid >> 6;
    const int wr = wid >> 2, wc = wid & 3;

    // R5 bijective XCD swizzle: contiguous m-major logical chunks per XCD
    const int nwg = gridDim.x;
    const int fb = blockIdx.x;
    const int logical = (fb & 7) * (nwg >> 3) + (fb >> 3);
    const int m0 = (logical / NT) * 256;
    const int n0 = (logical % NT) * 256;

    f32x4 acc[8][4];
#pragma unroll
    for (int i = 0; i < 8; i++)
#pragma unroll
        for (int j = 0; j < 4; j++) acc[i][j] = (f32x4){0.f, 0.f, 0.f, 0.f};

    const int kgrp = lane >> 4;
    const int la15 = lane & 15;
    int kx[2];
    kx[0] = ((kgrp)     ^ (lane & 7)) << 3;
    kx[1] = ((4 + kgrp) ^ (lane & 7)) << 3;

    // persistent per-thread staging pointers (swizzled source slot is
    // thread-constant: (lane&7)^(lane>>3))
    const int rstg = wid * 16 + (lane >> 3);
    const int cstg = ((lane & 7) ^ (lane >> 3)) << 3;
    const short* pA0  = A  + (size_t)(m0 + rstg) * lda + cstg;
    const short* pA0b = pA0 + (size_t)8 * lda;
    const short* pA1  = pA0 + (size_t)128 * lda;
    const short* pA1b = pA1 + (size_t)8 * lda;
    const short* pB0  = BT + (size_t)(n0 + rstg) * ldb + cstg;
    const short* pB0b = pB0 + (size_t)8 * ldb;
    const short* pB1  = pB0 + (size_t)128 * ldb;
    const short* pB1b = pB1 + (size_t)8 * ldb;
    short* dA[2][2]; short* dB[2][2];
#pragma unroll
    for (int b = 0; b < 2; b++) {
        dA[b][0] = &As[b][0][wid * 1024]; dA[b][1] = &As[b][1][wid * 1024];
        dB[b][0] = &Bs[b][0][wid * 1024]; dB[b][1] = &Bs[b][1][wid * 1024];
    }

    // prologue: A(0), A(1), B(0), B(1); leave B(1) in flight
    STG(pA0, pA0b, dA[0][0]); STG(pA1, pA1b, dA[0][1]); ADV_A();
    STG(pA0, pA0b, dA[1][0]); STG(pA1, pA1b, dA[1][1]); ADV_A();
    STG(pB0, pB0b, dB[0][0]); STG(pB1, pB1b, dB[0][1]); ADV_B();
    STG(pB0, pB0b, dB[1][0]); STG(pB1, pB1b, dB[1][1]); ADV_B();
    asm volatile("s_waitcnt vmcnt(4)" ::: "memory");
    __builtin_amdgcn_sched_barrier(0);
    __builtin_amdgcn_s_barrier();

    const int NP = K >> 7;   // iterations; each covers 2 K-tiles
    for (int I = 0; I < NP; ++I) {
        const bool nl = (I + 1 < NP);   // wave-uniform
        bf16x8 bfr[4][2], afA[2][2], afB[2][2];

        // ---- phase 1: tile T (buf0) q0 ; stage A(T+1) both halves
        READ_B(0); READ_AQ(0, 0, afA);
        if (I > 0) { STG(pA0, pA0b, dA[1][0]); STG(pA1, pA1b, dA[1][1]); ADV_A(); }
        asm volatile("s_waitcnt lgkmcnt(8)" ::: "memory");
        __builtin_amdgcn_sched_barrier(0);
        OPEN_PHASE();
        READ_AQ(0, 1, afB);          // prefetch q1 under MFMA(q0)
        MFMA16Q(0, afA);
        // ---- phase 2: q1 ; stage B(T+2)h0
        __builtin_amdgcn_s_barrier();
        if (nl) STG(pB0, pB0b, dB[0][0]);
        OPEN_PHASE();
        READ_AQ(0, 2, afA);
        MFMA16Q(1, afB);
        // ---- phase 3: q2 ; stage B(T+2)h1
        __builtin_amdgcn_s_barrier();
        if (nl) STG(pB1, pB1b, dB[0][1]);
        ADV_B();
        OPEN_PHASE();
        READ_AQ(0, 3, afB);
        MFMA16Q(2, afA);
        // ---- phase 4: q3 ; clean guard
        __builtin_amdgcn_s_barrier();
        OPEN_PHASE();
        MFMA16Q(3, afB);
        if (nl) { asm volatile("s_waitcnt vmcnt(4)" ::: "memory"); }
        else    { asm volatile("s_waitcnt vmcnt(0)" ::: "memory"); }
        __builtin_amdgcn_sched_barrier(0);
        // ---- phase 5: tile T+1 (buf1) q0 ; stage A(T+2) both halves
        __builtin_amdgcn_s_barrier();
        READ_B(1); READ_AQ(1, 0, afA);
        if (nl) { STG(pA0, pA0b, dA[0][0]); STG(pA1, pA1b, dA[0][1]); ADV_A(); }
        asm volatile("s_waitcnt lgkmcnt(8)" ::: "memory");
        __builtin_amdgcn_sched_barrier(0);
        OPEN_PHASE();
        READ_AQ(1, 1, afB);
        MFMA16Q(0, afA);
        // ---- phase 6: q1 ; stage B(T+3)h0
        __builtin_amdgcn_s_barrier();
        if (nl) STG(pB0, pB0b, dB[1][0]);
        OPEN_PHASE();
        READ_AQ(1, 2, afA);
        MFMA16Q(1, afB);
        // ---- phase 7: q2 ; stage B(T+3)h1
        __builtin_amdgcn_s_barrier();
        if (nl) STG(pB1, pB1b, dB[1][1]);
        ADV_B();
        OPEN_PHASE();
        READ_AQ(1, 3, afB);
        MFMA16Q(2, afA);
        // ---- phase 8: q3 ; clean guard
        __builtin_amdgcn_s_barrier();
        OPEN_PHASE();
        MFMA16Q(3, afB);
        if (nl) {
            asm volatile("s_waitcnt vmcnt(4)" ::: "memory");
            __builtin_amdgcn_sched_barrier(0);
            __builtin_amdgcn_s_barrier();
        }
    }

    // epilogue
    const int rbase = m0 + wr * 128 + ((lane >> 4) << 2);
    const int cbase = n0 + wc * 64 + la15;
#pragma unroll
    for (int mf = 0; mf < 8; ++mf) {
#pragma unroll
        for (int nf = 0; nf < 4; ++nf) {
            const int gn = cbase + nf * 16;
            const float bb = (EPI == 4) ? 0.f : bias[gn];
#pragma unroll
            for (int r = 0; r < 4; r++) {
                const int gm = rbase + mf * 16 + r;
                const size_t oidx = (size_t)gm * N + gn;
                float v = acc[mf][nf][r] + bb;
                if (EPI == 0) {
                    ((short*)outp)[oidx] = f2bf(v);
                } else if (EPI == 1) {
                    // non-temporal: H stream must not evict B from L3
                    __builtin_nontemporal_store(f2bf(fmaxf(v, 0.f)),
                                                &((short*)outp)[oidx]);
                } else if (EPI == 2 || EPI == 4) {
                    ((float*)outp)[oidx] = v + ((const float*)resid)[oidx];
                } else if (EPI == 3) {
                    ((float*)outp)[oidx] = v + bf2f(((const short*)resid)[oidx]);
                } else { // EPI == 5
                    ((short*)outp)[oidx] = f2bf(v + bf2f(((const short*)resid)[oidx]));
                }
            }
        }
    }
}

// ---------------- sparse 2-key attention gather (4 queries / block) ----------------
// KVb layout: [B*VLEN][2048], K features at cols 0..1023, V at 1024..2047
__global__ __launch_bounds__(256)
void attn_k(const short* __restrict__ Qb, const short* __restrict__ KVb,
            const int* __restrict__ rel, short* __restrict__ ctx)
{
    const int bq = blockIdx.x * 4 + (threadIdx.x >> 6);
    const int b = bq >> 9;           // Q = 512
    const int lane = threadIdx.x & 63;
    const int v0 = rel[bq * 2 + 0];
    const int v1 = rel[bq * 2 + 1];
    const short* qr  = Qb + (size_t)bq * DM;
    const short* k0r = KVb + (size_t)(b * VLEN + v0) * 2048;
    const short* k1r = KVb + (size_t)(b * VLEN + v1) * 2048;
    const short* v0r = k0r + 1024;
    const short* v1r = k1r + 1024;
    const int d0 = lane * 16;

    float q[16], ka[16], kc[16];
    {
        s16x8 a = *(const s16x8*)(qr + d0);
        s16x8 c = *(const s16x8*)(qr + d0 + 8);
#pragma unroll
        for (int i = 0; i < 8; i++) { q[i] = bf2f(a[i]); q[8 + i] = bf2f(c[i]); }
        a = *(const s16x8*)(k0r + d0); c = *(const s16x8*)(k0r + d0 + 8);
#pragma unroll
        for (int i = 0; i < 8; i++) { ka[i] = bf2f(a[i]); ka[8 + i] = bf2f(c[i]); }
        a = *(const s16x8*)(k1r + d0); c = *(const s16x8*)(k1r + d0 + 8);
#pragma unroll
        for (int i = 0; i < 8; i++) { kc[i] = bf2f(a[i]); kc[8 + i] = bf2f(c[i]); }
    }
    float s0 = 0.f, s1 = 0.f;
#pragma unroll
    for (int i = 0; i < 16; i++) { s0 += q[i] * ka[i]; s1 += q[i] * kc[i]; }
#pragma unroll
    for (int m = 1; m < 8; m <<= 1) { s0 += __shfl_xor(s0, m); s1 += __shfl_xor(s1, m); }
    const float sc = 0.08838834764831845f; // 1/sqrt(128)
    s0 *= sc; s1 *= sc;
    const float mx = fmaxf(s0, s1);
    const float e0 = __expf(s0 - mx), e1 = __expf(s1 - mx);
    const float inv = 1.f / (e0 + e1);
    const float w0 = e0 * inv, w1 = e1 * inv;

    float va[16], vb[16];
    {
        s16x8 a = *(const s16x8*)(v0r + d0); s16x8 c = *(const s16x8*)(v0r + d0 + 8);
#pragma unroll
        for (int i = 0; i < 8; i++) { va[i] = bf2f(a[i]); va[8 + i] = bf2f(c[i]); }
        a = *(const s16x8*)(v1r + d0); c = *(const s16x8*)(v1r + d0 + 8);
#pragma unroll
        for (int i = 0; i < 8; i++) { vb[i] = bf2f(a[i]); vb[8 + i] = bf2f(c[i]); }
    }
    s16x8 pa, pb;
#pragma unroll
    for (int i = 0; i < 8; i++) {
        pa[i] = f2bf(w0 * va[i] + w1 * vb[i]);
        pb[i] = f2bf(w0 * va[8 + i] + w1 * vb[8 + i]);
    }
    short* o = ctx + (size_t)bq * DM + d0;
    *(s16x8*)o = pa;
    *(s16x8*)(o + 8) = pb;
}

// ---------------- LayerNorm(ot_bf16 + pred_f32) -> bf16 ----------------
__global__ __launch_bounds__(256)
void lnr_k(const short* __restrict__ ot, const float* __restrict__ pr,
           const float* __restrict__ g, const float* __restrict__ bv,
           short* __restrict__ xb)
{
    const int row = blockIdx.x;
    const int tid = threadIdx.x;
    const s16x4 o4 = *(const s16x4*)(ot + (size_t)row * DM + tid * 4);
    const float4 p4 = *(const float4*)(pr + (size_t)row * DM + tid * 4);
    float x[4];
    x[0] = bf2f(o4[0]) + p4.x; x[1] = bf2f(o4[1]) + p4.y;
    x[2] = bf2f(o4[2]) + p4.z; x[3] = bf2f(o4[3]) + p4.w;
    float s = x[0] + x[1] + x[2] + x[3];
    float ss = x[0]*x[0] + x[1]*x[1] + x[2]*x[2] + x[3]*x[3];
#pragma unroll
    for (int m = 1; m < 64; m <<= 1) { s += __shfl_xor(s, m); ss += __shfl_xor(ss, m); }
    __shared__ float red[8];
    if ((tid & 63) == 0) { red[tid >> 6] = s; red[4 + (tid >> 6)] = ss; }
    __syncthreads();
    const float S = red[0] + red[1] + red[2] + red[3];
    const float SS = red[4] + red[5] + red[6] + red[7];
    const float mean = S * (1.f / DM);
    const float var = SS * (1.f / DM) - mean * mean;
    const float rstd = rsqrtf(var + 1e-5f);
    s16x4 p;
#pragma unroll
    for (int j = 0; j < 4; j++) {
        const int c = tid * 4 + j;
        p[j] = f2bf((x[j] - mean) * rstd * g[c] + bv[c]);
    }
    *(s16x4*)(xb + (size_t)row * DM + tid * 4) = p;
}

// ---------------- LayerNorm: bf16 in -> f32 out (non-temporal final write) ----------------
__global__ __launch_bounds__(256)
void ln2b_k(const short* __restrict__ in, const float* __restrict__ g,
            const float* __restrict__ bv, float* __restrict__ outp)
{
    const int row = blockIdx.x;
    const int tid = threadIdx.x;
    const s16x4 v4 = *(const s16x4*)(in + (size_t)row * DM + tid * 4);
    float x[4];
    x[0] = bf2f(v4[0]); x[1] = bf2f(v4[1]); x[2] = bf2f(v4[2]); x[3] = bf2f(v4[3]);
    float s = x[0] + x[1] + x[2] + x[3];
    float ss = x[0]*x[0] + x[1]*x[1] + x[2]*x[2] + x[3]*x[3];
#pragma unroll
    for (int m = 1; m < 64; m <<= 1) { s += __shfl_xor(s, m); ss += __shfl_xor(ss, m); }
    __shared__ float red[8];
    if ((tid & 63) == 0) { red[tid >> 6] = s; red[4 + (tid >> 6)] = ss; }
    __syncthreads();
    const float S = red[0] + red[1] + red[2] + red[3];
    const float SS = red[4] + red[5] + red[6] + red[7];
    const float mean = S * (1.f / DM);
    const float var = SS * (1.f / DM) - mean * mean;
    const float rstd = rsqrtf(var + 1e-5f);
    f32x4 o;
    o[0] = (x[0] - mean) * rstd * g[tid * 4 + 0] + bv[tid * 4 + 0];
    o[1] = (x[1] - mean) * rstd * g[tid * 4 + 1] + bv[tid * 4 + 1];
    o[2] = (x[2] - mean) * rstd * g[tid * 4 + 2] + bv[tid * 4 + 2];
    o[3] = (x[3] - mean) * rstd * g[tid * 4 + 3] + bv[tid * 4 + 3];
    __builtin_nontemporal_store(o, (f32x4*)(outp + (size_t)row * DM + tid * 4));
}

// ---------------- LayerNorm f32 in-place (split-H fallback path) ----------------
__global__ __launch_bounds__(256)
void ln_k(const float* __restrict__ in, const float* __restrict__ g,
          const float* __restrict__ bv, float* __restrict__ outp)
{
    const int row = blockIdx.x;
    const int tid = threadIdx.x;
    const float4 v = *(const float4*)(in + (size_t)row * DM + tid * 4);
    float s = v.x + v.y + v.z + v.w;
    float ss = v.x * v.x + v.y * v.y + v.z * v.z + v.w * v.w;
#pragma unroll
    for (int m = 1; m < 64; m <<= 1) { s += __shfl_xor(s, m); ss += __shfl_xor(ss, m); }
    __shared__ float red[8];
    if ((tid & 63) == 0) { red[tid >> 6] = s; red[4 + (tid >> 6)] = ss; }
    __syncthreads();
    const float S = red[0] + red[1] + red[2] + red[3];
    const float SS = red[4] + red[5] + red[6] + red[7];
    const float mean = S * (1.f / DM);
    const float var = SS * (1.f / DM) - mean * mean;
    const float rstd = rsqrtf(var + 1e-5f);
    float4 o;
    o.x = (v.x - mean) * rstd * g[tid * 4 + 0] + bv[tid * 4 + 0];
    o.y = (v.y - mean) * rstd * g[tid * 4 + 1] + bv[tid * 4 + 1];
    o.z = (v.z - mean) * rstd * g[tid * 4 + 2] + bv[tid * 4 + 2];
    o.w = (v.w - mean) * rstd * g[tid * 4 + 3] + bv[tid * 4 + 3];
    *(float4*)(outp + (size_t)row * DM + tid * 4) = o;
}

extern "C" void kernel_launch(void* const* d_in, const int* in_sizes, int n_in,
                              void* d_out, int out_size, void* d_ws, size_t ws_size,
                              hipStream_t stream)
{
    const float* pred = (const float*)d_in[0];
    const float* ent  = (const float*)d_in[1];
    const int*   rel  = (const int*)d_in[2];
    const float* w_q  = (const float*)d_in[3];
    const float* b_q  = (const float*)d_in[4];
    const float* w_k  = (const float*)d_in[5];
    const float* b_k  = (const float*)d_in[6];
    const float* w_v  = (const float*)d_in[7];
    const float* b_v  = (const float*)d_in[8];
    const float* w_o  = (const float*)d_in[9];
    const float* b_o  = (const float*)d_in[10];
    const float* ln1g = (const float*)d_in[11];
    const float* ln1b = (const float*)d_in[12];
    const float* w1   = (const float*)d_in[13];
    const float* b1   = (const float*)d_in[14];
    const float* w2   = (const float*)d_in[15];
    const float* b2   = (const float*)d_in[16];
    const float* ln2g = (const float*)d_in[17];
    const float* ln2b = (const float*)d_in[18];

    char* ws = (char*)d_ws;
    size_t off = 0;
    auto alloc = [&](size_t bytes) -> char* {
        char* p = ws + off;
        off += (bytes + 255) & ~(size_t)255;
        return p;
    };
    float* kvbias = (float*)alloc(2048 * 4);
    short* wqT  = (short*)alloc((size_t)1024 * 1024 * 2);
    short* wkvT = (short*)alloc((size_t)2048 * 1024 * 2);  // [2048][1024] (wk rows then wv rows)
    short* woT  = (short*)alloc((size_t)1024 * 1024 * 2);
    short* w1T  = (short*)alloc((size_t)4096 * 1024 * 2);  // [4096][1024]
    short* w2T  = (short*)alloc((size_t)1024 * 4096 * 2);  // [1024][4096]
    short* CTX  = (short*)alloc((size_t)BQTOT * DM * 2);   // entB -> ctx -> Xb
    short* KVb  = (short*)alloc((size_t)BVTOT * 2048 * 2); // [5120][2048]
    short* BIG  = (short*)alloc((size_t)BQTOT * 2048 * 2); // Qb+predB -> OT -> P2/H0
    const size_t offH = off;
    short* Hf   = (short*)(ws + offH);                     // [32768][4096] if it fits
    const bool fullH = ws_size >= offH + (size_t)BQTOT * 4096 * 2;

    short* Qb    = BIG;
    short* predB = BIG + (size_t)BQTOT * DM;
    short* entB  = CTX;
    short* OT    = BIG;                                    // Qb dead after attn
    short* P2    = BIG;                                    // OT dead after lnr (fullH)
    short* H0    = BIG;                                    // split-path FFN hidden
    short* Xb    = CTX;
    float* P     = (float*)d_out;                          // split-path f32 scratch

    // ---- small prep ----
    cat_k<<<8, 256, 0, stream>>>(b_k, b_v, kvbias, 1024);
    conv_k<<<(BQTOT * DM / 8 + 255) / 256, 256, 0, stream>>>(pred, predB, BQTOT * DM / 8);
    conv_k<<<(BVTOT * DM / 8 + 255) / 256, 256, 0, stream>>>(ent, entB, BVTOT * DM / 8);
    transp_k<<<dim3(32, 32), 256, 0, stream>>>(w_q, wqT, 1024, 1024);
    transp_k<<<dim3(32, 32), 256, 0, stream>>>(w_k, wkvT, 1024, 1024);
    transp_k<<<dim3(32, 32), 256, 0, stream>>>(w_v, wkvT + (size_t)1024 * 1024, 1024, 1024);
    transp_k<<<dim3(32, 32), 256, 0, stream>>>(w_o, woT, 1024, 1024);
    transp_k<<<dim3(128, 32), 256, 0, stream>>>(w1, w1T, 1024, 4096);
    transp_k<<<dim3(32, 128), 256, 0, stream>>>(w2, w2T, 4096, 1024);

    // ---- projections ----
    gemm7_k<0><<<512, 512, 0, stream>>>(predB, wqT, b_q, nullptr, Qb,
                                        BQTOT, 1024, 1024, 1024, 1024, 4);
    gemm7_k<0><<<160, 512, 0, stream>>>(entB, wkvT, kvbias, nullptr, KVb,
                                        BVTOT, 2048, 1024, 1024, 1024, 8);

    // ---- sparse attention ----
    attn_k<<<BQTOT / 4, 256, 0, stream>>>(Qb, KVb, rel, CTX);

    // ---- output proj (bf16, no resid) -> OT ; fused resid+LN1 -> Xb ----
    gemm7_k<0><<<512, 512, 0, stream>>>(CTX, woT, b_o, nullptr, OT,
                                        BQTOT, 1024, 1024, 1024, 1024, 4);
    lnr_k<<<BQTOT, 256, 0, stream>>>(OT, pred, ln1g, ln1b, Xb);

    if (fullH) {
        // ---- FFN, M-chunked into 2 halves; H writes non-temporal ----
        const int MH = BQTOT / 2;                          // 16384 rows per half
        for (int h = 0; h < 2; ++h) {
            short* xh = Xb + (size_t)h * MH * DM;
            short* hh = Hf + (size_t)h * MH * 4096;
            short* ph = P2 + (size_t)h * MH * DM;
            // FFN1-half: [16384 x 4096] = 1024 blocks (4/CU)
            gemm7_k<1><<<1024, 512, 0, stream>>>(xh, w1T, b1, nullptr, hh,
                                                 MH, 4096, 1024, 1024, 1024, 16);
            // FFN2-half: [16384 x 1024], K=4096 = 256 blocks (1/CU)
            gemm7_k<5><<<256, 512, 0, stream>>>(hh, w2T, b2, xh, ph,
                                                MH, 1024, 4096, 4096, 4096, 4);
            // LN2-half while P2-half is L3-hot
            ln2b_k<<<MH, 256, 0, stream>>>(ph, ln2g, ln2b,
                                           (float*)d_out + (size_t)h * MH * DM);
        }
    } else {
        // ---- FFN split into two D_INNER halves (f32 P path) ----
        gemm7_k<1><<<1024, 512, 0, stream>>>(Xb, w1T, b1, nullptr, H0,
                                             BQTOT, 2048, 1024, 1024, 1024, 8);
        gemm7_k<3><<<512, 512, 0, stream>>>(H0, w2T, b2, Xb, P,
                                            BQTOT, 1024, 2048, 2048, 4096, 4);
        gemm7_k<1><<<1024, 512, 0, stream>>>(Xb, w1T + (size_t)2048 * 1024, b1 + 2048,
                                             nullptr, H0,
                                             BQTOT, 2048, 1024, 1024, 1024, 8);
        gemm7_k<4><<<512, 512, 0, stream>>>(H0, w2T + 2048, b2, P, P,
                                            BQTOT, 1024, 2048, 2048, 4096, 4);
        ln_k<<<BQTOT, 256, 0, stream>>>(P, ln2g, ln2b, P);
    }
}

// Round 10
// 1068.316 us; speedup vs baseline: 1.0765x; 1.0765x over previous
//
#include <hip/hip_runtime.h>
#include <hip/hip_bf16.h>

#define DM 1024
#define QLEN 512
#define VLEN 80
#define BQTOT 32768   // B*Q
#define BVTOT 5120    // B*V

typedef __attribute__((ext_vector_type(8))) short s16x8;
typedef __attribute__((ext_vector_type(4))) short s16x4;
typedef __attribute__((ext_vector_type(4))) float f32x4;
typedef __attribute__((ext_vector_type(8))) __bf16 bf16x8;

__device__ inline short f2bf(float f) {
    __bf16 h = (__bf16)f;
    return __builtin_bit_cast(short, h);
}
__device__ inline float bf2f(short s) {
    unsigned u = ((unsigned)(unsigned short)s) << 16;
    return __builtin_bit_cast(float, u);
}

// ---------------- fp32 -> bf16 bulk convert (8 elems/thread) ----------------
__global__ __launch_bounds__(256)
void conv_k(const float* __restrict__ in, short* __restrict__ out, int n8)
{
    const int i = blockIdx.x * 256 + threadIdx.x;
    if (i >= n8) return;
    const float4 a = ((const float4*)in)[(size_t)i * 2];
    const float4 b = ((const float4*)in)[(size_t)i * 2 + 1];
    s16x8 p;
    p[0] = f2bf(a.x); p[1] = f2bf(a.y); p[2] = f2bf(a.z); p[3] = f2bf(a.w);
    p[4] = f2bf(b.x); p[5] = f2bf(b.y); p[6] = f2bf(b.z); p[7] = f2bf(b.w);
    ((s16x8*)out)[i] = p;
}

// ---------------- concat two fp32 vectors ----------------
__global__ __launch_bounds__(256)
void cat_k(const float* __restrict__ a, const float* __restrict__ b,
           float* __restrict__ o, int n)
{
    const int i = blockIdx.x * 256 + threadIdx.x;
    o[i] = (i < n) ? a[i] : b[i - n];
}

// ---------------- weight transpose + bf16 convert: W[K][N] -> WT[N][K] ----------------
__global__ __launch_bounds__(256)
void transp_k(const float* __restrict__ W, short* __restrict__ WT, int K, int N)
{
    __shared__ float s[32][33];
    const int n0 = blockIdx.x * 32, k0 = blockIdx.y * 32;
    const int tx = threadIdx.x & 31, ty = threadIdx.x >> 5;
#pragma unroll
    for (int j = 0; j < 4; j++)
        s[ty + j * 8][tx] = W[(size_t)(k0 + ty + j * 8) * N + n0 + tx];
    __syncthreads();
#pragma unroll
    for (int j = 0; j < 4; j++) {
        int r = ty + j * 8;
        WT[(size_t)(n0 + r) * K + k0 + tx] = f2bf(s[tx][r]);
    }
}

// ---------------- 256x256 8-phase bf16 MFMA GEMM body ----------------
// R5 XCD swizzle + pointer-increment staging + max-lead stage rotation;
// vmcnt(4) guards at ph4/ph8 only (never 0 mid-loop). Plain stores (R9
// showed nt on scattered 2B stores causes 2x write amplification).
// EPI:  0 = bf16 out = acc+bias
//       1 = bf16 out = relu(acc+bias)
//       2 = f32 out = acc+bias+resid_f32
//       3 = f32 out = acc+bias+resid_bf16
//       4 = f32 out = acc+resid_f32 (no bias)
//       5 = bf16 out = acc+bias+resid_bf16

#define STG(p, pb, d) do { \
    __builtin_amdgcn_global_load_lds((const __attribute__((address_space(1))) void*)(p), \
        (__attribute__((address_space(3))) void*)(d), 16, 0, 0); \
    __builtin_amdgcn_global_load_lds((const __attribute__((address_space(1))) void*)(pb), \
        (__attribute__((address_space(3))) void*)((d) + 512), 16, 0, 0); \
} while (0)

#define READ_B(db) do { \
    _Pragma("unroll") for (int n = 0; n < 4; n++) { \
        const int lb = ((wc & 1) << 6) + la15 + n * 16; \
        _Pragma("unroll") for (int ks = 0; ks < 2; ks++) \
            bfr[n][ks] = *(const bf16x8*)&Bs[db][wc >> 1][lb * 64 + kx[ks]]; \
    } } while (0)

#define READ_AQ(db, q, dst) do { \
    _Pragma("unroll") for (int mm = 0; mm < 2; mm++) { \
        const int lr2 = la15 + ((q) * 2 + mm) * 16; \
        _Pragma("unroll") for (int ks = 0; ks < 2; ks++) \
            dst[mm][ks] = *(const bf16x8*)&As[db][wr][lr2 * 64 + kx[ks]]; \
    } } while (0)

#define MFMA16Q(q, src) do { \
    __builtin_amdgcn_s_setprio(1); \
    _Pragma("unroll") for (int mm = 0; mm < 2; mm++) \
    _Pragma("unroll") for (int n = 0; n < 4; n++) \
    _Pragma("unroll") for (int ks = 0; ks < 2; ks++) \
        acc[(q) * 2 + mm][n] = __builtin_amdgcn_mfma_f32_16x16x32_bf16( \
            src[mm][ks], bfr[n][ks], acc[(q) * 2 + mm][n], 0, 0, 0); \
    __builtin_amdgcn_s_setprio(0); \
} while (0)

#define OPEN_PHASE() do { \
    __builtin_amdgcn_s_barrier(); \
    asm volatile("s_waitcnt lgkmcnt(0)" ::: "memory"); \
    __builtin_amdgcn_sched_barrier(0); \
} while (0)

#define ADV_A() do { pA0 += 64; pA0b += 64; pA1 += 64; pA1b += 64; } while (0)
#define ADV_B() do { pB0 += 64; pB0b += 64; pB1 += 64; pB1b += 64; } while (0)

typedef short lds2_t[2][8192];

template<int EPI>
__device__ __forceinline__
void gemm_body(short* AsRaw, short* BsRaw, int fb, int nwg,
               const short* __restrict__ A, const short* __restrict__ BT,
               const float* __restrict__ bias, const void* __restrict__ resid,
               void* __restrict__ outp, int N, int K, int lda, int ldb, int NT)
{
    lds2_t* As = (lds2_t*)AsRaw;     // As[kt parity][half][128*64]
    lds2_t* Bs = (lds2_t*)BsRaw;

    const int tid = threadIdx.x;
    const int lane = tid & 63;
    const int wid = tid >> 6;
    const int wr = wid >> 2, wc = wid & 3;

    // R5 bijective XCD swizzle: contiguous m-major logical chunks per XCD
    const int logical = (fb & 7) * (nwg >> 3) + (fb >> 3);
    const int m0 = (logical / NT) * 256;
    const int n0 = (logical % NT) * 256;

    f32x4 acc[8][4];
#pragma unroll
    for (int i = 0; i < 8; i++)
#pragma unroll
        for (int j = 0; j < 4; j++) acc[i][j] = (f32x4){0.f, 0.f, 0.f, 0.f};

    const int kgrp = lane >> 4;
    const int la15 = lane & 15;
    int kx[2];
    kx[0] = ((kgrp)     ^ (lane & 7)) << 3;
    kx[1] = ((4 + kgrp) ^ (lane & 7)) << 3;

    // persistent per-thread staging pointers (swizzled source slot is
    // thread-constant: (lane&7)^(lane>>3))
    const int rstg = wid * 16 + (lane >> 3);
    const int cstg = ((lane & 7) ^ (lane >> 3)) << 3;
    const short* pA0  = A  + (size_t)(m0 + rstg) * lda + cstg;
    const short* pA0b = pA0 + (size_t)8 * lda;
    const short* pA1  = pA0 + (size_t)128 * lda;
    const short* pA1b = pA1 + (size_t)8 * lda;
    const short* pB0  = BT + (size_t)(n0 + rstg) * ldb + cstg;
    const short* pB0b = pB0 + (size_t)8 * ldb;
    const short* pB1  = pB0 + (size_t)128 * ldb;
    const short* pB1b = pB1 + (size_t)8 * ldb;
    short* dA[2][2]; short* dB[2][2];
#pragma unroll
    for (int b = 0; b < 2; b++) {
        dA[b][0] = &As[b][0][wid * 1024]; dA[b][1] = &As[b][1][wid * 1024];
        dB[b][0] = &Bs[b][0][wid * 1024]; dB[b][1] = &Bs[b][1][wid * 1024];
    }

    // prologue: A(0), A(1), B(0), B(1); leave B(1) in flight
    STG(pA0, pA0b, dA[0][0]); STG(pA1, pA1b, dA[0][1]); ADV_A();
    STG(pA0, pA0b, dA[1][0]); STG(pA1, pA1b, dA[1][1]); ADV_A();
    STG(pB0, pB0b, dB[0][0]); STG(pB1, pB1b, dB[0][1]); ADV_B();
    STG(pB0, pB0b, dB[1][0]); STG(pB1, pB1b, dB[1][1]); ADV_B();
    asm volatile("s_waitcnt vmcnt(4)" ::: "memory");
    __builtin_amdgcn_sched_barrier(0);
    __builtin_amdgcn_s_barrier();

    const int NP = K >> 7;   // iterations; each covers 2 K-tiles
    for (int I = 0; I < NP; ++I) {
        const bool nl = (I + 1 < NP);   // wave-uniform
        bf16x8 bfr[4][2], afA[2][2], afB[2][2];

        // ---- phase 1: tile T (buf0) q0 ; stage A(T+1) both halves
        READ_B(0); READ_AQ(0, 0, afA);
        if (I > 0) { STG(pA0, pA0b, dA[1][0]); STG(pA1, pA1b, dA[1][1]); ADV_A(); }
        asm volatile("s_waitcnt lgkmcnt(8)" ::: "memory");
        __builtin_amdgcn_sched_barrier(0);
        OPEN_PHASE();
        READ_AQ(0, 1, afB);          // prefetch q1 under MFMA(q0)
        MFMA16Q(0, afA);
        // ---- phase 2: q1 ; stage B(T+2)h0
        __builtin_amdgcn_s_barrier();
        if (nl) STG(pB0, pB0b, dB[0][0]);
        OPEN_PHASE();
        READ_AQ(0, 2, afA);
        MFMA16Q(1, afB);
        // ---- phase 3: q2 ; stage B(T+2)h1
        __builtin_amdgcn_s_barrier();
        if (nl) STG(pB1, pB1b, dB[0][1]);
        ADV_B();
        OPEN_PHASE();
        READ_AQ(0, 3, afB);
        MFMA16Q(2, afA);
        // ---- phase 4: q3 ; clean guard
        __builtin_amdgcn_s_barrier();
        OPEN_PHASE();
        MFMA16Q(3, afB);
        if (nl) { asm volatile("s_waitcnt vmcnt(4)" ::: "memory"); }
        else    { asm volatile("s_waitcnt vmcnt(0)" ::: "memory"); }
        __builtin_amdgcn_sched_barrier(0);
        // ---- phase 5: tile T+1 (buf1) q0 ; stage A(T+2) both halves
        __builtin_amdgcn_s_barrier();
        READ_B(1); READ_AQ(1, 0, afA);
        if (nl) { STG(pA0, pA0b, dA[0][0]); STG(pA1, pA1b, dA[0][1]); ADV_A(); }
        asm volatile("s_waitcnt lgkmcnt(8)" ::: "memory");
        __builtin_amdgcn_sched_barrier(0);
        OPEN_PHASE();
        READ_AQ(1, 1, afB);
        MFMA16Q(0, afA);
        // ---- phase 6: q1 ; stage B(T+3)h0
        __builtin_amdgcn_s_barrier();
        if (nl) STG(pB0, pB0b, dB[1][0]);
        OPEN_PHASE();
        READ_AQ(1, 2, afA);
        MFMA16Q(1, afB);
        // ---- phase 7: q2 ; stage B(T+3)h1
        __builtin_amdgcn_s_barrier();
        if (nl) STG(pB1, pB1b, dB[1][1]);
        ADV_B();
        OPEN_PHASE();
        READ_AQ(1, 3, afB);
        MFMA16Q(2, afA);
        // ---- phase 8: q3 ; clean guard
        __builtin_amdgcn_s_barrier();
        OPEN_PHASE();
        MFMA16Q(3, afB);
        if (nl) {
            asm volatile("s_waitcnt vmcnt(4)" ::: "memory");
            __builtin_amdgcn_sched_barrier(0);
            __builtin_amdgcn_s_barrier();
        }
    }

    // epilogue
    const int rbase = m0 + wr * 128 + ((lane >> 4) << 2);
    const int cbase = n0 + wc * 64 + la15;
#pragma unroll
    for (int mf = 0; mf < 8; ++mf) {
#pragma unroll
        for (int nf = 0; nf < 4; ++nf) {
            const int gn = cbase + nf * 16;
            const float bb = (EPI == 4) ? 0.f : bias[gn];
#pragma unroll
            for (int r = 0; r < 4; r++) {
                const int gm = rbase + mf * 16 + r;
                const size_t oidx = (size_t)gm * N + gn;
                float v = acc[mf][nf][r] + bb;
                if (EPI == 0) {
                    ((short*)outp)[oidx] = f2bf(v);
                } else if (EPI == 1) {
                    ((short*)outp)[oidx] = f2bf(fmaxf(v, 0.f));
                } else if (EPI == 2 || EPI == 4) {
                    ((float*)outp)[oidx] = v + ((const float*)resid)[oidx];
                } else if (EPI == 3) {
                    ((float*)outp)[oidx] = v + bf2f(((const short*)resid)[oidx]);
                } else { // EPI == 5
                    ((short*)outp)[oidx] = f2bf(v + bf2f(((const short*)resid)[oidx]));
                }
            }
        }
    }
}

template<int EPI>
__global__ __launch_bounds__(512, 1)
void gemm7_k(const short* __restrict__ A, const short* __restrict__ BT,
             const float* __restrict__ bias, const void* __restrict__ resid,
             void* __restrict__ outp, int N, int K, int lda, int ldb, int NT)
{
    __shared__ __align__(16) short As[2][2][8192];
    __shared__ __align__(16) short Bs[2][2][8192];
    gemm_body<EPI>(&As[0][0][0], &Bs[0][0][0], blockIdx.x, gridDim.x,
                   A, BT, bias, resid, outp, N, K, lda, ldb, NT);
}

// Q-proj (blocks 0..511) and KV-proj (blocks 512..671) in one dispatch:
// KV blocks fill CUs during Q's tail instead of a serial launch.
__global__ __launch_bounds__(512, 1)
void gemm_qkv_k(const short* __restrict__ predB, const short* __restrict__ wqT,
                const float* __restrict__ bq, short* __restrict__ Qb,
                const short* __restrict__ entB, const short* __restrict__ wkvT,
                const float* __restrict__ kvb, short* __restrict__ KVb)
{
    __shared__ __align__(16) short As[2][2][8192];
    __shared__ __align__(16) short Bs[2][2][8192];
    if (blockIdx.x < 512) {
        gemm_body<0>(&As[0][0][0], &Bs[0][0][0], blockIdx.x, 512,
                     predB, wqT, bq, nullptr, Qb, 1024, 1024, 1024, 1024, 4);
    } else {
        gemm_body<0>(&As[0][0][0], &Bs[0][0][0], blockIdx.x - 512, 160,
                     entB, wkvT, kvb, nullptr, KVb, 2048, 1024, 1024, 1024, 8);
    }
}

// ---------------- sparse 2-key attention gather (4 queries / block) ----------------
// KVb layout: [B*VLEN][2048], K features at cols 0..1023, V at 1024..2047
__global__ __launch_bounds__(256)
void attn_k(const short* __restrict__ Qb, const short* __restrict__ KVb,
            const int* __restrict__ rel, short* __restrict__ ctx)
{
    const int bq = blockIdx.x * 4 + (threadIdx.x >> 6);
    const int b = bq >> 9;           // Q = 512
    const int lane = threadIdx.x & 63;
    const int v0 = rel[bq * 2 + 0];
    const int v1 = rel[bq * 2 + 1];
    const short* qr  = Qb + (size_t)bq * DM;
    const short* k0r = KVb + (size_t)(b * VLEN + v0) * 2048;
    const short* k1r = KVb + (size_t)(b * VLEN + v1) * 2048;
    const short* v0r = k0r + 1024;
    const short* v1r = k1r + 1024;
    const int d0 = lane * 16;

    float q[16], ka[16], kc[16];
    {
        s16x8 a = *(const s16x8*)(qr + d0);
        s16x8 c = *(const s16x8*)(qr + d0 + 8);
#pragma unroll
        for (int i = 0; i < 8; i++) { q[i] = bf2f(a[i]); q[8 + i] = bf2f(c[i]); }
        a = *(const s16x8*)(k0r + d0); c = *(const s16x8*)(k0r + d0 + 8);
#pragma unroll
        for (int i = 0; i < 8; i++) { ka[i] = bf2f(a[i]); ka[8 + i] = bf2f(c[i]); }
        a = *(const s16x8*)(k1r + d0); c = *(const s16x8*)(k1r + d0 + 8);
#pragma unroll
        for (int i = 0; i < 8; i++) { kc[i] = bf2f(a[i]); kc[8 + i] = bf2f(c[i]); }
    }
    float s0 = 0.f, s1 = 0.f;
#pragma unroll
    for (int i = 0; i < 16; i++) { s0 += q[i] * ka[i]; s1 += q[i] * kc[i]; }
#pragma unroll
    for (int m = 1; m < 8; m <<= 1) { s0 += __shfl_xor(s0, m); s1 += __shfl_xor(s1, m); }
    const float sc = 0.08838834764831845f; // 1/sqrt(128)
    s0 *= sc; s1 *= sc;
    const float mx = fmaxf(s0, s1);
    const float e0 = __expf(s0 - mx), e1 = __expf(s1 - mx);
    const float inv = 1.f / (e0 + e1);
    const float w0 = e0 * inv, w1 = e1 * inv;

    float va[16], vb[16];
    {
        s16x8 a = *(const s16x8*)(v0r + d0); s16x8 c = *(const s16x8*)(v0r + d0 + 8);
#pragma unroll
        for (int i = 0; i < 8; i++) { va[i] = bf2f(a[i]); va[8 + i] = bf2f(c[i]); }
        a = *(const s16x8*)(v1r + d0); c = *(const s16x8*)(v1r + d0 + 8);
#pragma unroll
        for (int i = 0; i < 8; i++) { vb[i] = bf2f(a[i]); vb[8 + i] = bf2f(c[i]); }
    }
    s16x8 pa, pb;
#pragma unroll
    for (int i = 0; i < 8; i++) {
        pa[i] = f2bf(w0 * va[i] + w1 * vb[i]);
        pb[i] = f2bf(w0 * va[8 + i] + w1 * vb[8 + i]);
    }
    short* o = ctx + (size_t)bq * DM + d0;
    *(s16x8*)o = pa;
    *(s16x8*)(o + 8) = pb;
}

// ---------------- LayerNorm bf16 in -> bf16 out (LN1) ----------------
__global__ __launch_bounds__(256)
void ln1b_k(const short* __restrict__ in, const float* __restrict__ g,
            const float* __restrict__ bv, short* __restrict__ outp)
{
    const int row = blockIdx.x;
    const int tid = threadIdx.x;
    const s16x4 v4 = *(const s16x4*)(in + (size_t)row * DM + tid * 4);
    float x[4];
    x[0] = bf2f(v4[0]); x[1] = bf2f(v4[1]); x[2] = bf2f(v4[2]); x[3] = bf2f(v4[3]);
    float s = x[0] + x[1] + x[2] + x[3];
    float ss = x[0]*x[0] + x[1]*x[1] + x[2]*x[2] + x[3]*x[3];
#pragma unroll
    for (int m = 1; m < 64; m <<= 1) { s += __shfl_xor(s, m); ss += __shfl_xor(ss, m); }
    __shared__ float red[8];
    if ((tid & 63) == 0) { red[tid >> 6] = s; red[4 + (tid >> 6)] = ss; }
    __syncthreads();
    const float S = red[0] + red[1] + red[2] + red[3];
    const float SS = red[4] + red[5] + red[6] + red[7];
    const float mean = S * (1.f / DM);
    const float var = SS * (1.f / DM) - mean * mean;
    const float rstd = rsqrtf(var + 1e-5f);
    s16x4 p;
#pragma unroll
    for (int j = 0; j < 4; j++) {
        const int c = tid * 4 + j;
        p[j] = f2bf((x[j] - mean) * rstd * g[c] + bv[c]);
    }
    *(s16x4*)(outp + (size_t)row * DM + tid * 4) = p;
}

// ---------------- LayerNorm: bf16 in -> f32 out (nt, coalesced 16B) ----------------
__global__ __launch_bounds__(256)
void ln2b_k(const short* __restrict__ in, const float* __restrict__ g,
            const float* __restrict__ bv, float* __restrict__ outp)
{
    const int row = blockIdx.x;
    const int tid = threadIdx.x;
    const s16x4 v4 = *(const s16x4*)(in + (size_t)row * DM + tid * 4);
    float x[4];
    x[0] = bf2f(v4[0]); x[1] = bf2f(v4[1]); x[2] = bf2f(v4[2]); x[3] = bf2f(v4[3]);
    float s = x[0] + x[1] + x[2] + x[3];
    float ss = x[0]*x[0] + x[1]*x[1] + x[2]*x[2] + x[3]*x[3];
#pragma unroll
    for (int m = 1; m < 64; m <<= 1) { s += __shfl_xor(s, m); ss += __shfl_xor(ss, m); }
    __shared__ float red[8];
    if ((tid & 63) == 0) { red[tid >> 6] = s; red[4 + (tid >> 6)] = ss; }
    __syncthreads();
    const float S = red[0] + red[1] + red[2] + red[3];
    const float SS = red[4] + red[5] + red[6] + red[7];
    const float mean = S * (1.f / DM);
    const float var = SS * (1.f / DM) - mean * mean;
    const float rstd = rsqrtf(var + 1e-5f);
    f32x4 o;
    o[0] = (x[0] - mean) * rstd * g[tid * 4 + 0] + bv[tid * 4 + 0];
    o[1] = (x[1] - mean) * rstd * g[tid * 4 + 1] + bv[tid * 4 + 1];
    o[2] = (x[2] - mean) * rstd * g[tid * 4 + 2] + bv[tid * 4 + 2];
    o[3] = (x[3] - mean) * rstd * g[tid * 4 + 3] + bv[tid * 4 + 3];
    __builtin_nontemporal_store(o, (f32x4*)(outp + (size_t)row * DM + tid * 4));
}

// ---------------- LayerNorm f32 in-place (split-H fallback path) ----------------
__global__ __launch_bounds__(256)
void ln_k(const float* __restrict__ in, const float* __restrict__ g,
          const float* __restrict__ bv, float* __restrict__ outp)
{
    const int row = blockIdx.x;
    const int tid = threadIdx.x;
    const float4 v = *(const float4*)(in + (size_t)row * DM + tid * 4);
    float s = v.x + v.y + v.z + v.w;
    float ss = v.x * v.x + v.y * v.y + v.z * v.z + v.w * v.w;
#pragma unroll
    for (int m = 1; m < 64; m <<= 1) { s += __shfl_xor(s, m); ss += __shfl_xor(ss, m); }
    __shared__ float red[8];
    if ((tid & 63) == 0) { red[tid >> 6] = s; red[4 + (tid >> 6)] = ss; }
    __syncthreads();
    const float S = red[0] + red[1] + red[2] + red[3];
    const float SS = red[4] + red[5] + red[6] + red[7];
    const float mean = S * (1.f / DM);
    const float var = SS * (1.f / DM) - mean * mean;
    const float rstd = rsqrtf(var + 1e-5f);
    float4 o;
    o.x = (v.x - mean) * rstd * g[tid * 4 + 0] + bv[tid * 4 + 0];
    o.y = (v.y - mean) * rstd * g[tid * 4 + 1] + bv[tid * 4 + 1];
    o.z = (v.z - mean) * rstd * g[tid * 4 + 2] + bv[tid * 4 + 2];
    o.w = (v.w - mean) * rstd * g[tid * 4 + 3] + bv[tid * 4 + 3];
    *(float4*)(outp + (size_t)row * DM + tid * 4) = o;
}

extern "C" void kernel_launch(void* const* d_in, const int* in_sizes, int n_in,
                              void* d_out, int out_size, void* d_ws, size_t ws_size,
                              hipStream_t stream)
{
    const float* pred = (const float*)d_in[0];
    const float* ent  = (const float*)d_in[1];
    const int*   rel  = (const int*)d_in[2];
    const float* w_q  = (const float*)d_in[3];
    const float* b_q  = (const float*)d_in[4];
    const float* w_k  = (const float*)d_in[5];
    const float* b_k  = (const float*)d_in[6];
    const float* w_v  = (const float*)d_in[7];
    const float* b_v  = (const float*)d_in[8];
    const float* w_o  = (const float*)d_in[9];
    const float* b_o  = (const float*)d_in[10];
    const float* ln1g = (const float*)d_in[11];
    const float* ln1b = (const float*)d_in[12];
    const float* w1   = (const float*)d_in[13];
    const float* b1   = (const float*)d_in[14];
    const float* w2   = (const float*)d_in[15];
    const float* b2   = (const float*)d_in[16];
    const float* ln2g = (const float*)d_in[17];
    const float* ln2b = (const float*)d_in[18];

    char* ws = (char*)d_ws;
    size_t off = 0;
    auto alloc = [&](size_t bytes) -> char* {
        char* p = ws + off;
        off += (bytes + 255) & ~(size_t)255;
        return p;
    };
    float* kvbias = (float*)alloc(2048 * 4);
    short* wqT  = (short*)alloc((size_t)1024 * 1024 * 2);
    short* wkvT = (short*)alloc((size_t)2048 * 1024 * 2);  // [2048][1024] (wk rows then wv rows)
    short* woT  = (short*)alloc((size_t)1024 * 1024 * 2);
    short* w1T  = (short*)alloc((size_t)4096 * 1024 * 2);  // [4096][1024]
    short* w2T  = (short*)alloc((size_t)1024 * 4096 * 2);  // [1024][4096]
    short* CTX  = (short*)alloc((size_t)BQTOT * DM * 2);   // entB -> ctx -> Xb
    short* KVb  = (short*)alloc((size_t)BVTOT * 2048 * 2); // [5120][2048]
    short* BIG  = (short*)alloc((size_t)BQTOT * 2048 * 2); // Qb+predB -> OT -> P2/H0
    const size_t offH = off;
    short* Hf   = (short*)(ws + offH);                     // [32768][4096] if it fits
    const bool fullH = ws_size >= offH + (size_t)BQTOT * 4096 * 2;

    short* Qb    = BIG;
    short* predB = BIG + (size_t)BQTOT * DM;
    short* entB  = CTX;
    short* OT    = BIG;                                    // Qb dead after attn
    short* P2    = BIG;                                    // OT dead after ln1b (fullH)
    short* H0    = BIG;                                    // split-path FFN hidden
    short* Xb    = CTX;
    float* P     = (float*)d_out;                          // split-path f32 scratch

    // ---- small prep ----
    cat_k<<<8, 256, 0, stream>>>(b_k, b_v, kvbias, 1024);
    conv_k<<<(BQTOT * DM / 8 + 255) / 256, 256, 0, stream>>>(pred, predB, BQTOT * DM / 8);
    conv_k<<<(BVTOT * DM / 8 + 255) / 256, 256, 0, stream>>>(ent, entB, BVTOT * DM / 8);
    transp_k<<<dim3(32, 32), 256, 0, stream>>>(w_q, wqT, 1024, 1024);
    transp_k<<<dim3(32, 32), 256, 0, stream>>>(w_k, wkvT, 1024, 1024);
    transp_k<<<dim3(32, 32), 256, 0, stream>>>(w_v, wkvT + (size_t)1024 * 1024, 1024, 1024);
    transp_k<<<dim3(32, 32), 256, 0, stream>>>(w_o, woT, 1024, 1024);
    transp_k<<<dim3(128, 32), 256, 0, stream>>>(w1, w1T, 1024, 4096);
    transp_k<<<dim3(32, 128), 256, 0, stream>>>(w2, w2T, 4096, 1024);

    // ---- Q + KV projections (one combined dispatch) ----
    gemm_qkv_k<<<672, 512, 0, stream>>>(predB, wqT, b_q, Qb, entB, wkvT, kvbias, KVb);

    // ---- sparse attention ----
    attn_k<<<BQTOT / 4, 256, 0, stream>>>(Qb, KVb, rel, CTX);

    // ---- output proj with fused predB residual -> OT (bf16 pre-LN1) ----
    gemm7_k<5><<<512, 512, 0, stream>>>(CTX, woT, b_o, predB, OT,
                                        1024, 1024, 1024, 1024, 4);
    ln1b_k<<<BQTOT, 256, 0, stream>>>(OT, ln1g, ln1b, Xb);

    if (fullH) {
        // ---- FFN, M-chunked into 2 halves (H-half L3-resident) ----
        const int MH = BQTOT / 2;                          // 16384 rows per half
        for (int h = 0; h < 2; ++h) {
            short* xh = Xb + (size_t)h * MH * DM;
            short* hh = Hf + (size_t)h * MH * 4096;
            short* ph = P2 + (size_t)h * MH * DM;
            gemm7_k<1><<<1024, 512, 0, stream>>>(xh, w1T, b1, nullptr, hh,
                                                 4096, 1024, 1024, 1024, 16);
            gemm7_k<5><<<256, 512, 0, stream>>>(hh, w2T, b2, xh, ph,
                                                1024, 4096, 4096, 4096, 4);
            ln2b_k<<<MH, 256, 0, stream>>>(ph, ln2g, ln2b,
                                           (float*)d_out + (size_t)h * MH * DM);
        }
    } else {
        // ---- FFN split into two D_INNER halves (f32 P path) ----
        gemm7_k<1><<<1024, 512, 0, stream>>>(Xb, w1T, b1, nullptr, H0,
                                             2048, 1024, 1024, 1024, 8);
        gemm7_k<3><<<512, 512, 0, stream>>>(H0, w2T, b2, Xb, P,
                                            1024, 2048, 2048, 4096, 4);
        gemm7_k<1><<<1024, 512, 0, stream>>>(Xb, w1T + (size_t)2048 * 1024, b1 + 2048,
                                             nullptr, H0,
                                             2048, 1024, 1024, 1024, 8);
        gemm7_k<4><<<512, 512, 0, stream>>>(H0, w2T + 2048, b2, P, P,
                                            1024, 2048, 2048, 4096, 4);
        ln_k<<<BQTOT, 256, 0, stream>>>(P, ln2g, ln2b, P);
    }
}

// Round 11
// 863.563 us; speedup vs baseline: 1.3317x; 1.2371x over previous
//
#include <hip/hip_runtime.h>
#include <hip/hip_bf16.h>

#define DM 1024
#define QLEN 512
#define VLEN 80
#define BQTOT 32768   // B*Q
#define BVTOT 5120    // B*V

typedef __attribute__((ext_vector_type(8))) short s16x8;
typedef __attribute__((ext_vector_type(4))) short s16x4;
typedef __attribute__((ext_vector_type(4))) float f32x4;
typedef __attribute__((ext_vector_type(8))) __bf16 bf16x8;

__device__ inline short f2bf(float f) {
    __bf16 h = (__bf16)f;
    return __builtin_bit_cast(short, h);
}
__device__ inline float bf2f(short s) {
    unsigned u = ((unsigned)(unsigned short)s) << 16;
    return __builtin_bit_cast(float, u);
}

// ---------------- fp32 -> bf16 bulk convert (8 elems/thread) ----------------
__global__ __launch_bounds__(256)
void conv_k(const float* __restrict__ in, short* __restrict__ out, int n8)
{
    const int i = blockIdx.x * 256 + threadIdx.x;
    if (i >= n8) return;
    const float4 a = ((const float4*)in)[(size_t)i * 2];
    const float4 b = ((const float4*)in)[(size_t)i * 2 + 1];
    s16x8 p;
    p[0] = f2bf(a.x); p[1] = f2bf(a.y); p[2] = f2bf(a.z); p[3] = f2bf(a.w);
    p[4] = f2bf(b.x); p[5] = f2bf(b.y); p[6] = f2bf(b.z); p[7] = f2bf(b.w);
    ((s16x8*)out)[i] = p;
}

// ---------------- concat two fp32 vectors ----------------
__global__ __launch_bounds__(256)
void cat_k(const float* __restrict__ a, const float* __restrict__ b,
           float* __restrict__ o, int n)
{
    const int i = blockIdx.x * 256 + threadIdx.x;
    o[i] = (i < n) ? a[i] : b[i - n];
}

// ---------------- weight transpose + bf16 convert: W[K][N] -> WT[N][K] ----------------
__global__ __launch_bounds__(256)
void transp_k(const float* __restrict__ W, short* __restrict__ WT, int K, int N)
{
    __shared__ float s[32][33];
    const int n0 = blockIdx.x * 32, k0 = blockIdx.y * 32;
    const int tx = threadIdx.x & 31, ty = threadIdx.x >> 5;
#pragma unroll
    for (int j = 0; j < 4; j++)
        s[ty + j * 8][tx] = W[(size_t)(k0 + ty + j * 8) * N + n0 + tx];
    __syncthreads();
#pragma unroll
    for (int j = 0; j < 4; j++) {
        int r = ty + j * 8;
        WT[(size_t)(n0 + r) * K + k0 + tx] = f2bf(s[tx][r]);
    }
}

// ---------------- 256x256 8-phase bf16 MFMA GEMM body ----------------
// R5 XCD swizzle + pointer-increment staging + max-lead stage rotation;
// vmcnt(4) guards at ph4/ph8 only. bf16-out EPIs use an LDS-staged epilogue:
// C tile through the (reused) 128KB LDS buffer -> coalesced 16B stores
// (enables nt on the H stream without R9's 2B-scatter write amplification).
// EPI:  0 = bf16 out = acc+bias
//       1 = bf16 out = relu(acc+bias)   [nt 16B stores]
//       2 = f32 out = acc+bias+resid_f32
//       3 = f32 out = acc+bias+resid_bf16
//       4 = f32 out = acc+resid_f32 (no bias)
//       5 = bf16 out = acc+bias+resid_bf16

#define STG(p, pb, d) do { \
    __builtin_amdgcn_global_load_lds((const __attribute__((address_space(1))) void*)(p), \
        (__attribute__((address_space(3))) void*)(d), 16, 0, 0); \
    __builtin_amdgcn_global_load_lds((const __attribute__((address_space(1))) void*)(pb), \
        (__attribute__((address_space(3))) void*)((d) + 512), 16, 0, 0); \
} while (0)

#define READ_B(db) do { \
    _Pragma("unroll") for (int n = 0; n < 4; n++) { \
        const int lb = ((wc & 1) << 6) + la15 + n * 16; \
        _Pragma("unroll") for (int ks = 0; ks < 2; ks++) \
            bfr[n][ks] = *(const bf16x8*)&Bs[db][wc >> 1][lb * 64 + kx[ks]]; \
    } } while (0)

#define READ_AQ(db, q, dst) do { \
    _Pragma("unroll") for (int mm = 0; mm < 2; mm++) { \
        const int lr2 = la15 + ((q) * 2 + mm) * 16; \
        _Pragma("unroll") for (int ks = 0; ks < 2; ks++) \
            dst[mm][ks] = *(const bf16x8*)&As[db][wr][lr2 * 64 + kx[ks]]; \
    } } while (0)

#define MFMA16Q(q, src) do { \
    __builtin_amdgcn_s_setprio(1); \
    _Pragma("unroll") for (int mm = 0; mm < 2; mm++) \
    _Pragma("unroll") for (int n = 0; n < 4; n++) \
    _Pragma("unroll") for (int ks = 0; ks < 2; ks++) \
        acc[(q) * 2 + mm][n] = __builtin_amdgcn_mfma_f32_16x16x32_bf16( \
            src[mm][ks], bfr[n][ks], acc[(q) * 2 + mm][n], 0, 0, 0); \
    __builtin_amdgcn_s_setprio(0); \
} while (0)

#define OPEN_PHASE() do { \
    __builtin_amdgcn_s_barrier(); \
    asm volatile("s_waitcnt lgkmcnt(0)" ::: "memory"); \
    __builtin_amdgcn_sched_barrier(0); \
} while (0)

#define ADV_A() do { pA0 += 64; pA0b += 64; pA1 += 64; pA1b += 64; } while (0)
#define ADV_B() do { pB0 += 64; pB0b += 64; pB1 += 64; pB1b += 64; } while (0)

typedef short lds2_t[2][8192];

template<int EPI>
__device__ __forceinline__
void gemm_body(short* ldsRaw, int fb, int nwg,
               const short* __restrict__ A, const short* __restrict__ BT,
               const float* __restrict__ bias, const void* __restrict__ resid,
               void* __restrict__ outp, int N, int K, int lda, int ldb, int NT)
{
    lds2_t* As = (lds2_t*)ldsRaw;             // [2][2][8192]
    lds2_t* Bs = (lds2_t*)(ldsRaw + 32768);

    const int tid = threadIdx.x;
    const int lane = tid & 63;
    const int wid = tid >> 6;
    const int wr = wid >> 2, wc = wid & 3;

    // R5 bijective XCD swizzle: contiguous m-major logical chunks per XCD
    const int logical = (fb & 7) * (nwg >> 3) + (fb >> 3);
    const int m0 = (logical / NT) * 256;
    const int n0 = (logical % NT) * 256;

    f32x4 acc[8][4];
#pragma unroll
    for (int i = 0; i < 8; i++)
#pragma unroll
        for (int j = 0; j < 4; j++) acc[i][j] = (f32x4){0.f, 0.f, 0.f, 0.f};

    const int kgrp = lane >> 4;
    const int la15 = lane & 15;
    int kx[2];
    kx[0] = ((kgrp)     ^ (lane & 7)) << 3;
    kx[1] = ((4 + kgrp) ^ (lane & 7)) << 3;

    // persistent per-thread staging pointers
    const int rstg = wid * 16 + (lane >> 3);
    const int cstg = ((lane & 7) ^ (lane >> 3)) << 3;
    const short* pA0  = A  + (size_t)(m0 + rstg) * lda + cstg;
    const short* pA0b = pA0 + (size_t)8 * lda;
    const short* pA1  = pA0 + (size_t)128 * lda;
    const short* pA1b = pA1 + (size_t)8 * lda;
    const short* pB0  = BT + (size_t)(n0 + rstg) * ldb + cstg;
    const short* pB0b = pB0 + (size_t)8 * ldb;
    const short* pB1  = pB0 + (size_t)128 * ldb;
    const short* pB1b = pB1 + (size_t)8 * ldb;
    short* dA[2][2]; short* dB[2][2];
#pragma unroll
    for (int b = 0; b < 2; b++) {
        dA[b][0] = &As[b][0][wid * 1024]; dA[b][1] = &As[b][1][wid * 1024];
        dB[b][0] = &Bs[b][0][wid * 1024]; dB[b][1] = &Bs[b][1][wid * 1024];
    }

    // prologue: A(0), A(1), B(0), B(1); leave B(1) in flight
    STG(pA0, pA0b, dA[0][0]); STG(pA1, pA1b, dA[0][1]); ADV_A();
    STG(pA0, pA0b, dA[1][0]); STG(pA1, pA1b, dA[1][1]); ADV_A();
    STG(pB0, pB0b, dB[0][0]); STG(pB1, pB1b, dB[0][1]); ADV_B();
    STG(pB0, pB0b, dB[1][0]); STG(pB1, pB1b, dB[1][1]); ADV_B();
    asm volatile("s_waitcnt vmcnt(4)" ::: "memory");
    __builtin_amdgcn_sched_barrier(0);
    __builtin_amdgcn_s_barrier();

    const int NP = K >> 7;   // iterations; each covers 2 K-tiles
    for (int I = 0; I < NP; ++I) {
        const bool nl = (I + 1 < NP);   // wave-uniform
        bf16x8 bfr[4][2], afA[2][2], afB[2][2];

        // ---- phase 1: tile T (buf0) q0 ; stage A(T+1) both halves
        READ_B(0); READ_AQ(0, 0, afA);
        if (I > 0) { STG(pA0, pA0b, dA[1][0]); STG(pA1, pA1b, dA[1][1]); ADV_A(); }
        asm volatile("s_waitcnt lgkmcnt(8)" ::: "memory");
        __builtin_amdgcn_sched_barrier(0);
        OPEN_PHASE();
        READ_AQ(0, 1, afB);          // prefetch q1 under MFMA(q0)
        MFMA16Q(0, afA);
        // ---- phase 2: q1 ; stage B(T+2)h0
        __builtin_amdgcn_s_barrier();
        if (nl) STG(pB0, pB0b, dB[0][0]);
        OPEN_PHASE();
        READ_AQ(0, 2, afA);
        MFMA16Q(1, afB);
        // ---- phase 3: q2 ; stage B(T+2)h1
        __builtin_amdgcn_s_barrier();
        if (nl) STG(pB1, pB1b, dB[0][1]);
        ADV_B();
        OPEN_PHASE();
        READ_AQ(0, 3, afB);
        MFMA16Q(2, afA);
        // ---- phase 4: q3 ; clean guard
        __builtin_amdgcn_s_barrier();
        OPEN_PHASE();
        MFMA16Q(3, afB);
        if (nl) { asm volatile("s_waitcnt vmcnt(4)" ::: "memory"); }
        else    { asm volatile("s_waitcnt vmcnt(0)" ::: "memory"); }
        __builtin_amdgcn_sched_barrier(0);
        // ---- phase 5: tile T+1 (buf1) q0 ; stage A(T+2) both halves
        __builtin_amdgcn_s_barrier();
        READ_B(1); READ_AQ(1, 0, afA);
        if (nl) { STG(pA0, pA0b, dA[0][0]); STG(pA1, pA1b, dA[0][1]); ADV_A(); }
        asm volatile("s_waitcnt lgkmcnt(8)" ::: "memory");
        __builtin_amdgcn_sched_barrier(0);
        OPEN_PHASE();
        READ_AQ(1, 1, afB);
        MFMA16Q(0, afA);
        // ---- phase 6: q1 ; stage B(T+3)h0
        __builtin_amdgcn_s_barrier();
        if (nl) STG(pB0, pB0b, dB[1][0]);
        OPEN_PHASE();
        READ_AQ(1, 2, afA);
        MFMA16Q(1, afB);
        // ---- phase 7: q2 ; stage B(T+3)h1
        __builtin_amdgcn_s_barrier();
        if (nl) STG(pB1, pB1b, dB[1][1]);
        ADV_B();
        OPEN_PHASE();
        READ_AQ(1, 3, afB);
        MFMA16Q(2, afA);
        // ---- phase 8: q3 ; clean guard
        __builtin_amdgcn_s_barrier();
        OPEN_PHASE();
        MFMA16Q(3, afB);
        if (nl) {
            asm volatile("s_waitcnt vmcnt(4)" ::: "memory");
            __builtin_amdgcn_sched_barrier(0);
            __builtin_amdgcn_s_barrier();
        }
    }

    if constexpr (EPI == 0 || EPI == 1 || EPI == 5) {
        // ---- LDS-staged epilogue: coalesced 16B stores ----
        short* Cl = ldsRaw;   // 256x256 bf16, slot-swizzled (slot ^= (row>>2)&7)
        __syncthreads();      // all waves drained their LDS reads before here
        const int rb = wr * 128 + ((lane >> 4) << 2);
        const int cb = wc * 64 + la15;
#pragma unroll
        for (int mf = 0; mf < 8; ++mf) {
#pragma unroll
            for (int nf = 0; nf < 4; ++nf) {
                const int lc = cb + nf * 16;
                const float bb = bias[n0 + lc];
#pragma unroll
                for (int r = 0; r < 4; ++r) {
                    const int lr = rb + mf * 16 + r;
                    const int slot = (lc >> 3) ^ ((lr >> 2) & 7);
                    Cl[lr * 256 + slot * 8 + (lc & 7)] = f2bf(acc[mf][nf][r] + bb);
                }
            }
        }
        __syncthreads();
#pragma unroll
        for (int ps = 0; ps < 16; ++ps) {
            const int row = ps * 16 + (tid >> 5);
            const int sl = (tid & 31) ^ ((row >> 2) & 7);
            s16x8 v8 = *(const s16x8*)&Cl[row * 256 + sl * 8];
            const size_t gidx = (size_t)(m0 + row) * N + n0 + (tid & 31) * 8;
            if (EPI == 1) {
#pragma unroll
                for (int j = 0; j < 8; j++)
                    v8[j] = (short)((v8[j] & (short)0x8000) ? 0 : v8[j]);
                __builtin_nontemporal_store(v8, (s16x8*)((short*)outp + gidx));
            } else if (EPI == 5) {
                s16x8 rr = *(const s16x8*)((const short*)resid + gidx);
#pragma unroll
                for (int j = 0; j < 8; j++)
                    v8[j] = f2bf(bf2f(v8[j]) + bf2f(rr[j]));
                *(s16x8*)((short*)outp + gidx) = v8;
            } else {
                *(s16x8*)((short*)outp + gidx) = v8;
            }
        }
    } else {
        // f32-out fallback epilogue (scalar stores)
        const int rbase = m0 + wr * 128 + ((lane >> 4) << 2);
        const int cbase = n0 + wc * 64 + la15;
#pragma unroll
        for (int mf = 0; mf < 8; ++mf) {
#pragma unroll
            for (int nf = 0; nf < 4; ++nf) {
                const int gn = cbase + nf * 16;
                const float bb = (EPI == 4) ? 0.f : bias[gn];
#pragma unroll
                for (int r = 0; r < 4; r++) {
                    const int gm = rbase + mf * 16 + r;
                    const size_t oidx = (size_t)gm * N + gn;
                    float v = acc[mf][nf][r] + bb;
                    if (EPI == 2 || EPI == 4) {
                        ((float*)outp)[oidx] = v + ((const float*)resid)[oidx];
                    } else { // EPI == 3
                        ((float*)outp)[oidx] = v + bf2f(((const short*)resid)[oidx]);
                    }
                }
            }
        }
    }
}

template<int EPI>
__global__ __launch_bounds__(512, 1)
void gemm7_k(const short* __restrict__ A, const short* __restrict__ BT,
             const float* __restrict__ bias, const void* __restrict__ resid,
             void* __restrict__ outp, int N, int K, int lda, int ldb, int NT)
{
    __shared__ __align__(16) short LDSB[65536];   // 128 KB
    gemm_body<EPI>(LDSB, blockIdx.x, gridDim.x,
                   A, BT, bias, resid, outp, N, K, lda, ldb, NT);
}

// Q-proj (blocks 0..511) and KV-proj (blocks 512..671) in one dispatch.
__global__ __launch_bounds__(512, 1)
void gemm_qkv_k(const short* __restrict__ predB, const short* __restrict__ wqT,
                const float* __restrict__ bq, short* __restrict__ Qb,
                const short* __restrict__ entB, const short* __restrict__ wkvT,
                const float* __restrict__ kvb, short* __restrict__ KVb)
{
    __shared__ __align__(16) short LDSB[65536];
    if (blockIdx.x < 512) {
        gemm_body<0>(LDSB, blockIdx.x, 512,
                     predB, wqT, bq, nullptr, Qb, 1024, 1024, 1024, 1024, 4);
    } else {
        gemm_body<0>(LDSB, blockIdx.x - 512, 160,
                     entB, wkvT, kvb, nullptr, KVb, 2048, 1024, 1024, 1024, 8);
    }
}

// ---------------- sparse 2-key attention gather (4 queries / block) ----------------
// KVb layout: [B*VLEN][2048], K features at cols 0..1023, V at 1024..2047
__global__ __launch_bounds__(256)
void attn_k(const short* __restrict__ Qb, const short* __restrict__ KVb,
            const int* __restrict__ rel, short* __restrict__ ctx)
{
    const int bq = blockIdx.x * 4 + (threadIdx.x >> 6);
    const int b = bq >> 9;           // Q = 512
    const int lane = threadIdx.x & 63;
    const int v0 = rel[bq * 2 + 0];
    const int v1 = rel[bq * 2 + 1];
    const short* qr  = Qb + (size_t)bq * DM;
    const short* k0r = KVb + (size_t)(b * VLEN + v0) * 2048;
    const short* k1r = KVb + (size_t)(b * VLEN + v1) * 2048;
    const short* v0r = k0r + 1024;
    const short* v1r = k1r + 1024;
    const int d0 = lane * 16;

    float q[16], ka[16], kc[16];
    {
        s16x8 a = *(const s16x8*)(qr + d0);
        s16x8 c = *(const s16x8*)(qr + d0 + 8);
#pragma unroll
        for (int i = 0; i < 8; i++) { q[i] = bf2f(a[i]); q[8 + i] = bf2f(c[i]); }
        a = *(const s16x8*)(k0r + d0); c = *(const s16x8*)(k0r + d0 + 8);
#pragma unroll
        for (int i = 0; i < 8; i++) { ka[i] = bf2f(a[i]); ka[8 + i] = bf2f(c[i]); }
        a = *(const s16x8*)(k1r + d0); c = *(const s16x8*)(k1r + d0 + 8);
#pragma unroll
        for (int i = 0; i < 8; i++) { kc[i] = bf2f(a[i]); kc[8 + i] = bf2f(c[i]); }
    }
    float s0 = 0.f, s1 = 0.f;
#pragma unroll
    for (int i = 0; i < 16; i++) { s0 += q[i] * ka[i]; s1 += q[i] * kc[i]; }
#pragma unroll
    for (int m = 1; m < 8; m <<= 1) { s0 += __shfl_xor(s0, m); s1 += __shfl_xor(s1, m); }
    const float sc = 0.08838834764831845f; // 1/sqrt(128)
    s0 *= sc; s1 *= sc;
    const float mx = fmaxf(s0, s1);
    const float e0 = __expf(s0 - mx), e1 = __expf(s1 - mx);
    const float inv = 1.f / (e0 + e1);
    const float w0 = e0 * inv, w1 = e1 * inv;

    float va[16], vb[16];
    {
        s16x8 a = *(const s16x8*)(v0r + d0); s16x8 c = *(const s16x8*)(v0r + d0 + 8);
#pragma unroll
        for (int i = 0; i < 8; i++) { va[i] = bf2f(a[i]); va[8 + i] = bf2f(c[i]); }
        a = *(const s16x8*)(v1r + d0); c = *(const s16x8*)(v1r + d0 + 8);
#pragma unroll
        for (int i = 0; i < 8; i++) { vb[i] = bf2f(a[i]); vb[8 + i] = bf2f(c[i]); }
    }
    s16x8 pa, pb;
#pragma unroll
    for (int i = 0; i < 8; i++) {
        pa[i] = f2bf(w0 * va[i] + w1 * vb[i]);
        pb[i] = f2bf(w0 * va[8 + i] + w1 * vb[8 + i]);
    }
    short* o = ctx + (size_t)bq * DM + d0;
    *(s16x8*)o = pa;
    *(s16x8*)(o + 8) = pb;
}

// ---------------- LayerNorm bf16 in -> bf16 out (LN1) ----------------
__global__ __launch_bounds__(256)
void ln1b_k(const short* __restrict__ in, const float* __restrict__ g,
            const float* __restrict__ bv, short* __restrict__ outp)
{
    const int row = blockIdx.x;
    const int tid = threadIdx.x;
    const s16x4 v4 = *(const s16x4*)(in + (size_t)row * DM + tid * 4);
    float x[4];
    x[0] = bf2f(v4[0]); x[1] = bf2f(v4[1]); x[2] = bf2f(v4[2]); x[3] = bf2f(v4[3]);
    float s = x[0] + x[1] + x[2] + x[3];
    float ss = x[0]*x[0] + x[1]*x[1] + x[2]*x[2] + x[3]*x[3];
#pragma unroll
    for (int m = 1; m < 64; m <<= 1) { s += __shfl_xor(s, m); ss += __shfl_xor(ss, m); }
    __shared__ float red[8];
    if ((tid & 63) == 0) { red[tid >> 6] = s; red[4 + (tid >> 6)] = ss; }
    __syncthreads();
    const float S = red[0] + red[1] + red[2] + red[3];
    const float SS = red[4] + red[5] + red[6] + red[7];
    const float mean = S * (1.f / DM);
    const float var = SS * (1.f / DM) - mean * mean;
    const float rstd = rsqrtf(var + 1e-5f);
    s16x4 p;
#pragma unroll
    for (int j = 0; j < 4; j++) {
        const int c = tid * 4 + j;
        p[j] = f2bf((x[j] - mean) * rstd * g[c] + bv[c]);
    }
    *(s16x4*)(outp + (size_t)row * DM + tid * 4) = p;
}

// ---------------- LayerNorm: bf16 in -> f32 out (nt, coalesced 16B) ----------------
__global__ __launch_bounds__(256)
void ln2b_k(const short* __restrict__ in, const float* __restrict__ g,
            const float* __restrict__ bv, float* __restrict__ outp)
{
    const int row = blockIdx.x;
    const int tid = threadIdx.x;
    const s16x4 v4 = *(const s16x4*)(in + (size_t)row * DM + tid * 4);
    float x[4];
    x[0] = bf2f(v4[0]); x[1] = bf2f(v4[1]); x[2] = bf2f(v4[2]); x[3] = bf2f(v4[3]);
    float s = x[0] + x[1] + x[2] + x[3];
    float ss = x[0]*x[0] + x[1]*x[1] + x[2]*x[2] + x[3]*x[3];
#pragma unroll
    for (int m = 1; m < 64; m <<= 1) { s += __shfl_xor(s, m); ss += __shfl_xor(ss, m); }
    __shared__ float red[8];
    if ((tid & 63) == 0) { red[tid >> 6] = s; red[4 + (tid >> 6)] = ss; }
    __syncthreads();
    const float S = red[0] + red[1] + red[2] + red[3];
    const float SS = red[4] + red[5] + red[6] + red[7];
    const float mean = S * (1.f / DM);
    const float var = SS * (1.f / DM) - mean * mean;
    const float rstd = rsqrtf(var + 1e-5f);
    f32x4 o;
    o[0] = (x[0] - mean) * rstd * g[tid * 4 + 0] + bv[tid * 4 + 0];
    o[1] = (x[1] - mean) * rstd * g[tid * 4 + 1] + bv[tid * 4 + 1];
    o[2] = (x[2] - mean) * rstd * g[tid * 4 + 2] + bv[tid * 4 + 2];
    o[3] = (x[3] - mean) * rstd * g[tid * 4 + 3] + bv[tid * 4 + 3];
    __builtin_nontemporal_store(o, (f32x4*)(outp + (size_t)row * DM + tid * 4));
}

// ---------------- LayerNorm f32 in-place (split-H fallback path) ----------------
__global__ __launch_bounds__(256)
void ln_k(const float* __restrict__ in, const float* __restrict__ g,
          const float* __restrict__ bv, float* __restrict__ outp)
{
    const int row = blockIdx.x;
    const int tid = threadIdx.x;
    const float4 v = *(const float4*)(in + (size_t)row * DM + tid * 4);
    float s = v.x + v.y + v.z + v.w;
    float ss = v.x * v.x + v.y * v.y + v.z * v.z + v.w * v.w;
#pragma unroll
    for (int m = 1; m < 64; m <<= 1) { s += __shfl_xor(s, m); ss += __shfl_xor(ss, m); }
    __shared__ float red[8];
    if ((tid & 63) == 0) { red[tid >> 6] = s; red[4 + (tid >> 6)] = ss; }
    __syncthreads();
    const float S = red[0] + red[1] + red[2] + red[3];
    const float SS = red[4] + red[5] + red[6] + red[7];
    const float mean = S * (1.f / DM);
    const float var = SS * (1.f / DM) - mean * mean;
    const float rstd = rsqrtf(var + 1e-5f);
    float4 o;
    o.x = (v.x - mean) * rstd * g[tid * 4 + 0] + bv[tid * 4 + 0];
    o.y = (v.y - mean) * rstd * g[tid * 4 + 1] + bv[tid * 4 + 1];
    o.z = (v.z - mean) * rstd * g[tid * 4 + 2] + bv[tid * 4 + 2];
    o.w = (v.w - mean) * rstd * g[tid * 4 + 3] + bv[tid * 4 + 3];
    *(float4*)(outp + (size_t)row * DM + tid * 4) = o;
}

extern "C" void kernel_launch(void* const* d_in, const int* in_sizes, int n_in,
                              void* d_out, int out_size, void* d_ws, size_t ws_size,
                              hipStream_t stream)
{
    const float* pred = (const float*)d_in[0];
    const float* ent  = (const float*)d_in[1];
    const int*   rel  = (const int*)d_in[2];
    const float* w_q  = (const float*)d_in[3];
    const float* b_q  = (const float*)d_in[4];
    const float* w_k  = (const float*)d_in[5];
    const float* b_k  = (const float*)d_in[6];
    const float* w_v  = (const float*)d_in[7];
    const float* b_v  = (const float*)d_in[8];
    const float* w_o  = (const float*)d_in[9];
    const float* b_o  = (const float*)d_in[10];
    const float* ln1g = (const float*)d_in[11];
    const float* ln1b = (const float*)d_in[12];
    const float* w1   = (const float*)d_in[13];
    const float* b1   = (const float*)d_in[14];
    const float* w2   = (const float*)d_in[15];
    const float* b2   = (const float*)d_in[16];
    const float* ln2g = (const float*)d_in[17];
    const float* ln2b = (const float*)d_in[18];

    char* ws = (char*)d_ws;
    size_t off = 0;
    auto alloc = [&](size_t bytes) -> char* {
        char* p = ws + off;
        off += (bytes + 255) & ~(size_t)255;
        return p;
    };
    float* kvbias = (float*)alloc(2048 * 4);
    short* wqT  = (short*)alloc((size_t)1024 * 1024 * 2);
    short* wkvT = (short*)alloc((size_t)2048 * 1024 * 2);  // [2048][1024] (wk rows then wv rows)
    short* woT  = (short*)alloc((size_t)1024 * 1024 * 2);
    short* w1T  = (short*)alloc((size_t)4096 * 1024 * 2);  // [4096][1024]
    short* w2T  = (short*)alloc((size_t)1024 * 4096 * 2);  // [1024][4096]
    short* CTX  = (short*)alloc((size_t)BQTOT * DM * 2);   // entB -> ctx -> Xb
    short* KVb  = (short*)alloc((size_t)BVTOT * 2048 * 2); // [5120][2048]
    short* BIG  = (short*)alloc((size_t)BQTOT * 2048 * 2); // Qb+predB -> OT -> P2/H0
    const size_t offH = off;
    short* Hf   = (short*)(ws + offH);                     // [32768][4096] if it fits
    const bool fullH = ws_size >= offH + (size_t)BQTOT * 4096 * 2;

    short* Qb    = BIG;
    short* predB = BIG + (size_t)BQTOT * DM;
    short* entB  = CTX;
    short* OT    = BIG;                                    // Qb dead after attn
    short* P2    = BIG;                                    // OT dead after ln1b (fullH)
    short* H0    = BIG;                                    // split-path FFN hidden
    short* Xb    = CTX;
    float* P     = (float*)d_out;                          // split-path f32 scratch

    // ---- small prep ----
    cat_k<<<8, 256, 0, stream>>>(b_k, b_v, kvbias, 1024);
    conv_k<<<(BQTOT * DM / 8 + 255) / 256, 256, 0, stream>>>(pred, predB, BQTOT * DM / 8);
    conv_k<<<(BVTOT * DM / 8 + 255) / 256, 256, 0, stream>>>(ent, entB, BVTOT * DM / 8);
    transp_k<<<dim3(32, 32), 256, 0, stream>>>(w_q, wqT, 1024, 1024);
    transp_k<<<dim3(32, 32), 256, 0, stream>>>(w_k, wkvT, 1024, 1024);
    transp_k<<<dim3(32, 32), 256, 0, stream>>>(w_v, wkvT + (size_t)1024 * 1024, 1024, 1024);
    transp_k<<<dim3(32, 32), 256, 0, stream>>>(w_o, woT, 1024, 1024);
    transp_k<<<dim3(128, 32), 256, 0, stream>>>(w1, w1T, 1024, 4096);
    transp_k<<<dim3(32, 128), 256, 0, stream>>>(w2, w2T, 4096, 1024);

    // ---- Q + KV projections (one combined dispatch) ----
    gemm_qkv_k<<<672, 512, 0, stream>>>(predB, wqT, b_q, Qb, entB, wkvT, kvbias, KVb);

    // ---- sparse attention ----
    attn_k<<<BQTOT / 4, 256, 0, stream>>>(Qb, KVb, rel, CTX);

    // ---- output proj with fused predB residual -> OT (bf16 pre-LN1) ----
    gemm7_k<5><<<512, 512, 0, stream>>>(CTX, woT, b_o, predB, OT,
                                        1024, 1024, 1024, 1024, 4);
    ln1b_k<<<BQTOT, 256, 0, stream>>>(OT, ln1g, ln1b, Xb);

    if (fullH) {
        // ---- FFN, M-chunked into 2 halves (H-half L3-resident; nt H-writes) ----
        const int MH = BQTOT / 2;                          // 16384 rows per half
        for (int h = 0; h < 2; ++h) {
            short* xh = Xb + (size_t)h * MH * DM;
            short* hh = Hf + (size_t)h * MH * 4096;
            short* ph = P2 + (size_t)h * MH * DM;
            gemm7_k<1><<<1024, 512, 0, stream>>>(xh, w1T, b1, nullptr, hh,
                                                 4096, 1024, 1024, 1024, 16);
            gemm7_k<5><<<256, 512, 0, stream>>>(hh, w2T, b2, xh, ph,
                                                1024, 4096, 4096, 4096, 4);
            ln2b_k<<<MH, 256, 0, stream>>>(ph, ln2g, ln2b,
                                           (float*)d_out + (size_t)h * MH * DM);
        }
    } else {
        // ---- FFN split into two D_INNER halves (f32 P path) ----
        gemm7_k<1><<<1024, 512, 0, stream>>>(Xb, w1T, b1, nullptr, H0,
                                             2048, 1024, 1024, 1024, 8);
        gemm7_k<3><<<512, 512, 0, stream>>>(H0, w2T, b2, Xb, P,
                                            1024, 2048, 2048, 4096, 4);
        gemm7_k<1><<<1024, 512, 0, stream>>>(Xb, w1T + (size_t)2048 * 1024, b1 + 2048,
                                             nullptr, H0,
                                             2048, 1024, 1024, 1024, 8);
        gemm7_k<4><<<512, 512, 0, stream>>>(H0, w2T + 2048, b2, P, P,
                                            1024, 2048, 2048, 4096, 4);
        ln_k<<<BQTOT, 256, 0, stream>>>(P, ln2g, ln2b, P);
    }
}